// Round 1
// baseline (582.374 us; speedup 1.0000x reference)
//
#include <hip/hip_runtime.h>

// out[n, i] = b[n, i] * sum_j a[n, j]
// B = L = 8192, fp32. Purely memory-bound: 768 MiB total traffic -> ~128 us
// at 6.3 TB/s achievable HBM BW.
//
// One block per row: 256 threads, each handles 8 float4 (L/4/256 = 8).
// Phase 1: vectorized load of a-row + block reduction (wave shuffle + LDS).
// Phase 2: vectorized load of b-row, scale by row sum, vectorized store.

constexpr int L = 8192;
constexpr int BLOCK = 256;
constexpr int VEC_PER_THREAD = L / 4 / BLOCK;  // 8

__global__ __launch_bounds__(BLOCK) void outer_row_scale_kernel(
    const float* __restrict__ a,
    const float* __restrict__ b,
    float* __restrict__ out) {
    const size_t row = blockIdx.x;
    const float4* __restrict__ arow = reinterpret_cast<const float4*>(a + row * L);
    const float4* __restrict__ brow = reinterpret_cast<const float4*>(b + row * L);
    float4* __restrict__ orow = reinterpret_cast<float4*>(out + row * L);

    const int tid = threadIdx.x;

    // --- Phase 1: row sum of a ---
    float s = 0.0f;
    float4 va[VEC_PER_THREAD];
#pragma unroll
    for (int k = 0; k < VEC_PER_THREAD; ++k) {
        va[k] = arow[tid + k * BLOCK];  // coalesced: lane i -> 16B at base+16*i
    }
#pragma unroll
    for (int k = 0; k < VEC_PER_THREAD; ++k) {
        s += (va[k].x + va[k].y) + (va[k].z + va[k].w);
    }

    // Wave-64 shuffle reduction
#pragma unroll
    for (int off = 32; off > 0; off >>= 1) {
        s += __shfl_down(s, off, 64);
    }

    __shared__ float wave_sums[BLOCK / 64];  // 4 waves per block
    const int lane = tid & 63;
    const int wave = tid >> 6;
    if (lane == 0) wave_sums[wave] = s;
    __syncthreads();

    const float total = (wave_sums[0] + wave_sums[1]) + (wave_sums[2] + wave_sums[3]);

    // --- Phase 2: out = b * total ---
#pragma unroll
    for (int k = 0; k < VEC_PER_THREAD; ++k) {
        float4 vb = brow[tid + k * BLOCK];
        float4 vo;
        vo.x = vb.x * total;
        vo.y = vb.y * total;
        vo.z = vb.z * total;
        vo.w = vb.w * total;
        orow[tid + k * BLOCK] = vo;
    }
}

extern "C" void kernel_launch(void* const* d_in, const int* in_sizes, int n_in,
                              void* d_out, int out_size, void* d_ws, size_t ws_size,
                              hipStream_t stream) {
    const float* a = (const float*)d_in[0];
    const float* b = (const float*)d_in[1];
    float* out = (float*)d_out;
    const int B = in_sizes[0] / L;  // 8192
    outer_row_scale_kernel<<<B, BLOCK, 0, stream>>>(a, b, out);
}